// Round 2
// baseline (687.138 us; speedup 1.0000x reference)
//
#include <hip/hip_runtime.h>
#include <math.h>

// Shapes (fixed)
#define BB 2
#define HH 16
#define SS 2048
#define DD 1024
#define DK 64
#define BHS (BB*HH*SS)          // 65536
#define QSCALE 0.04508422f      // log2(e)/sqrt(1024): folded into q so softmax uses exp2

typedef short  bf16x8  __attribute__((ext_vector_type(8)));
typedef float  floatx4 __attribute__((ext_vector_type(4)));
typedef unsigned short u16;

#define MFMA(a,b,c) __builtin_amdgcn_mfma_f32_16x16x32_bf16((a),(b),(c),0,0,0)

// hardware packed conversion: dst.lo = bf16(lo), dst.hi = bf16(hi), RNE
__device__ __forceinline__ unsigned cvt_pk_bf16(float lo, float hi) {
    unsigned r;
    asm("v_cvt_pk_bf16_f32 %0, %1, %2" : "=v"(r) : "v"(lo), "v"(hi));
    return r;
}
__device__ __forceinline__ bf16x8 ldfrag(const u16* p) {
    union { uint4 u; bf16x8 b; } c;
    c.u = *(const uint4*)p;
    return c.b;
}
__device__ __forceinline__ void stbf4(u16* p, float4 t) {  // 4xf32 -> 4xbf16, 8B store
    union { unsigned u[2]; uint2 v; } c;
    c.u[0] = cvt_pk_bf16(t.x, t.y);
    c.u[1] = cvt_pk_bf16(t.z, t.w);
    *(uint2*)p = c.v;
}
// 4 f32 -> bf16 at p[0], p[16], p[32], p[48]  (C-fragment col stride 16)
__device__ __forceinline__ void st4s(u16* p, float a, float b, float c, float d) {
    unsigned x = cvt_pk_bf16(a, b), y = cvt_pk_bf16(c, d);
    p[0]  = (u16)x; p[16] = (u16)(x >> 16);
    p[32] = (u16)y; p[48] = (u16)(y >> 16);
}
// 2 f32 -> bf16 at p[0], p[16]
__device__ __forceinline__ void st2s(u16* p, float a, float b) {
    unsigned x = cvt_pk_bf16(a, b);
    p[0]  = (u16)x; p[16] = (u16)(x >> 16);
}

// ---------------------------------------------------------------------------
// Kernel 0: one-shot weight conversion fp32->bf16 (tiny: ~5 MB read).
// ---------------------------------------------------------------------------
#define WQKV_CHUNKS (192*1024/4)     // 49152 float4 chunks
#define WO_CHUNKS   (1024*1024/4)    // 262144
__global__ __launch_bounds__(256) void convert_w(
    const float* __restrict__ wq, const float* __restrict__ wk,
    const float* __restrict__ wv, const float* __restrict__ wo,
    u16* __restrict__ wqkv, u16* __restrict__ wo_bf)
{
    int i = blockIdx.x * 256 + threadIdx.x;
    if (i < WQKV_CHUNKS) {
        int r = i >> 8;            // row 0..191 (256 float4 per row)
        int c = i & 255;
        const float* src = (r < 64) ? wq : ((r < 128) ? wk : wv);
        float4 t = *(const float4*)(src + (size_t)(r & 63) * DD + c * 4);
        stbf4(wqkv + (size_t)r * DD + c * 4, t);
    } else if (i < WQKV_CHUNKS + WO_CHUNKS) {
        int j = i - WQKV_CHUNKS;
        float4 t = *(const float4*)(wo + (size_t)j * 4);
        stbf4(wo_bf + (size_t)j * 4, t);
    }
}

// ---------------------------------------------------------------------------
// Kernel 1: QKV projection. 512 thr (8 waves), BM=64 rows.
// X staged in column-QUARTERS (64 rows x 256 cols): 1 KB contiguous per row
// per stage (vs 256 B before -> DRAM-friendly), reg-pipelined one quarter
// ahead (T14). W tile (192x64) reg-prefetched one k-step ahead.
// Wave w: row-tile (w&3), n-tiles (w>>2)*6 .. +5  (n: 0-3 q, 4-7 k, 8-11 v).
// ---------------------------------------------------------------------------
__global__ __launch_bounds__(512, 4) void qkv_proj(
    const float* __restrict__ x, const u16* __restrict__ wqkv,
    u16* __restrict__ q, u16* __restrict__ k, u16* __restrict__ vT)
{
    __shared__ __align__(16) u16 Xs[64][264];   // 33.8 KB, quarter panel (+8 pad)
    __shared__ __align__(16) u16 Ws[192][72];   // 27.6 KB
    const int tid  = threadIdx.x;
    const int w    = tid >> 6;
    const int lane = tid & 63;
    const int quad = lane >> 4;
    const int l16  = lane & 15;
    const int rt   = w & 3;
    const int g    = w >> 2;
    const int rowbase = blockIdx.x * 64;
    const float* xb = x + (size_t)rowbase * DD;

    float4 xreg[8];
    uint4  wreg[3];

    auto xload = [&](int qd) {
#pragma unroll
        for (int it = 0; it < 8; ++it) {
            int li = tid + it * 512;
            int r  = li >> 6, c4 = li & 63;          // 1 KB contiguous per row
            xreg[it] = *(const float4*)(xb + (size_t)r * DD + qd * 256 + c4 * 4);
        }
    };
    auto xstore = [&]() {
#pragma unroll
        for (int it = 0; it < 8; ++it) {
            int li = tid + it * 512;
            int r  = li >> 6, c4 = li & 63;
            stbf4(&Xs[r][c4 * 4], xreg[it]);
        }
    };
    auto wload = [&](int kk) {
#pragma unroll
        for (int it = 0; it < 3; ++it) {
            int li = tid + it * 512;
            int r  = li >> 3, c8 = li & 7;
            wreg[it] = *(const uint4*)(wqkv + (size_t)r * DD + kk * 64 + c8 * 8);
        }
    };
    auto wstore = [&]() {
#pragma unroll
        for (int it = 0; it < 3; ++it) {
            int li = tid + it * 512;
            int r  = li >> 3, c8 = li & 7;
            *(uint4*)&Ws[r][c8 * 8] = wreg[it];
        }
    };

    floatx4 acc[6];
#pragma unroll
    for (int j = 0; j < 6; ++j) acc[j] = (floatx4){0.f,0.f,0.f,0.f};

    xload(0); xstore();
    wload(0); wstore();
    __syncthreads();

    for (int qd = 0; qd < 4; ++qd) {
        if (qd < 3) xload(qd + 1);                   // next quarter in flight
#pragma unroll
        for (int ks = 0; ks < 4; ++ks) {
            int kk = qd * 4 + ks;
            if (kk < 15) wload(kk + 1);              // next W tile in flight
            bf16x8 a0 = ldfrag(&Xs[rt * 16 + l16][ks * 64 + quad * 8]);
            bf16x8 a1 = ldfrag(&Xs[rt * 16 + l16][ks * 64 + 32 + quad * 8]);
#pragma unroll
            for (int j = 0; j < 6; ++j) {
                int n = g * 6 + j;
                bf16x8 b0 = ldfrag(&Ws[n * 16 + l16][quad * 8]);
                bf16x8 b1 = ldfrag(&Ws[n * 16 + l16][32 + quad * 8]);
                acc[j] = MFMA(a0, b0, acc[j]);
                acc[j] = MFMA(a1, b1, acc[j]);
            }
            __syncthreads();                          // everyone done reading
            if (kk < 15) wstore();
            if (ks == 3 && qd < 3) xstore();
            __syncthreads();                          // tiles ready
        }
    }

    // epilogue: global row = rowbase + rt*16 + quad*4 + rr; col = n*16 + l16
#pragma unroll
    for (int rr = 0; rr < 4; ++rr) {
        int rloc = rt * 16 + quad * 4 + rr;
        size_t m = (size_t)(rowbase + rloc);
        if (g == 0) {
            st4s(&q[m * DK + l16], acc[0][rr] * QSCALE, acc[1][rr] * QSCALE,
                                   acc[2][rr] * QSCALE, acc[3][rr] * QSCALE);
            st2s(&k[m * DK + l16], acc[4][rr], acc[5][rr]);          // k cols 0..31
        } else {
            st2s(&k[m * DK + 32 + l16], acc[0][rr], acc[1][rr]);     // k cols 32..63
            st4s(&Xs[rloc][l16], acc[2][rr], acc[3][rr],             // v -> Vbuf
                                 acc[4][rr], acc[5][rr]);
        }
    }
    __syncthreads();
    {   // vT[(bh*64+dk)*2048 + s] transpose write, 16 B per thread
        const int dk = tid >> 3;
        const int sc = (tid & 7) * 8;
        const int bh = rowbase >> 11;
        const int s0 = rowbase & 2047;
        union { u16 s[8]; uint4 u; } t;
#pragma unroll
        for (int u = 0; u < 8; ++u) t.s[u] = Xs[sc + u][dk];
        *(uint4*)(vT + ((size_t)(bh * DK + dk)) * SS + s0 + sc) = t.u;
    }
}

// ---------------------------------------------------------------------------
// Kernel 2: flash attention, online softmax in log2 domain, T14 K/V prefetch:
// next tile's K/V global loads are in flight during QK/softmax/PV of the
// current tile; LDS write happens between two barriers (no exposed latency).
// ---------------------------------------------------------------------------
__global__ __launch_bounds__(256, 4) void flash_attn(
    const u16* __restrict__ q, const u16* __restrict__ k,
    const u16* __restrict__ vT, u16* __restrict__ ao)
{
    __shared__ __align__(16) u16 Qs[64][72];
    __shared__ __align__(16) u16 Ks[64][72];
    __shared__ __align__(16) u16 Vt[64][72];       // Vt[dk][t]
    __shared__ __align__(16) u16 Ps[4][16][72];    // per-wave P tile
    const int tid  = threadIdx.x;
    const int w    = tid >> 6;
    const int lane = tid & 63;
    const int quad = lane >> 4;
    const int l16  = lane & 15;
    const int qt   = blockIdx.x;
    const int bh   = blockIdx.y;
    const size_t kbase = (size_t)bh * SS * DK;     // q,k layout [bh*S + t][64]
    const size_t vbase = (size_t)bh * DK * SS;     // vT layout [bh*64 + dk][S]

    uint4 kreg[2], vreg[2];
    auto kvload = [&](int kt) {
#pragma unroll
        for (int it = 0; it < 2; ++it) {
            int li = tid + it * 256;
            int r  = li >> 3, c8 = li & 7;
            kreg[it] = *(const uint4*)(k + kbase + (size_t)(kt * 64 + r) * DK + c8 * 8);
            vreg[it] = *(const uint4*)(vT + vbase + (size_t)r * SS + kt * 64 + c8 * 8);
        }
    };
    auto kvstore = [&]() {
#pragma unroll
        for (int it = 0; it < 2; ++it) {
            int li = tid + it * 256;
            int r  = li >> 3, c8 = li & 7;
            *(uint4*)&Ks[r][c8 * 8] = kreg[it];
            *(uint4*)&Vt[r][c8 * 8] = vreg[it];
        }
    };

    // load Q tile once (512 uint4 chunks, 2/thread)
#pragma unroll
    for (int it = 0; it < 2; ++it) {
        int li = tid + it * 256;
        int r  = li >> 3, c8 = li & 7;
        *(uint4*)&Qs[r][c8 * 8] =
            *(const uint4*)(q + kbase + (size_t)(qt * 64 + r) * DK + c8 * 8);
    }

    float m_i[4], l_i[4];
    floatx4 acc_o[4];
#pragma unroll
    for (int r = 0; r < 4; ++r) { m_i[r] = -INFINITY; l_i[r] = 0.f; }
#pragma unroll
    for (int n = 0; n < 4; ++n) acc_o[n] = (floatx4){0.f,0.f,0.f,0.f};

    kvload(0); kvstore();
    __syncthreads();

    for (int kt = 0; kt < SS / 64; ++kt) {
        if (kt < SS / 64 - 1) kvload(kt + 1);       // next K/V in flight

        // scores (log2 units)
        floatx4 sc[4];
        __builtin_amdgcn_s_setprio(1);
        {
            bf16x8 a0 = ldfrag(&Qs[w * 16 + l16][quad * 8]);
            bf16x8 a1 = ldfrag(&Qs[w * 16 + l16][32 + quad * 8]);
#pragma unroll
            for (int n = 0; n < 4; ++n) {
                sc[n] = (floatx4){0.f,0.f,0.f,0.f};
                bf16x8 b0 = ldfrag(&Ks[n * 16 + l16][quad * 8]);
                bf16x8 b1 = ldfrag(&Ks[n * 16 + l16][32 + quad * 8]);
                sc[n] = MFMA(a0, b0, sc[n]);
                sc[n] = MFMA(a1, b1, sc[n]);
            }
        }
        __builtin_amdgcn_s_setprio(0);

        // row maxima (row = quad*4+r), 16-lane butterfly
        float rmx[4];
#pragma unroll
        for (int r = 0; r < 4; ++r) {
            float rm = fmaxf(fmaxf(sc[0][r], sc[1][r]), fmaxf(sc[2][r], sc[3][r]));
#pragma unroll
            for (int off = 1; off < 16; off <<= 1)
                rm = fmaxf(rm, __shfl_xor(rm, off, 64));
            rmx[r] = rm;
        }
        // defer-max (THR=8 in log2 units)
        int ok = (rmx[0] <= m_i[0] + 8.f) & (rmx[1] <= m_i[1] + 8.f) &
                 (rmx[2] <= m_i[2] + 8.f) & (rmx[3] <= m_i[3] + 8.f);
        if (!__all(ok)) {
#pragma unroll
            for (int r = 0; r < 4; ++r) {
                float mnew  = fmaxf(m_i[r], rmx[r]);
                float alpha = __builtin_amdgcn_exp2f(m_i[r] - mnew);
#pragma unroll
                for (int n = 0; n < 4; ++n) acc_o[n][r] *= alpha;
                l_i[r] *= alpha;
                m_i[r]  = mnew;
            }
        }
        // P = exp2(S - m), row sums, P -> LDS
#pragma unroll
        for (int r = 0; r < 4; ++r) {
            float mi = m_i[r];
            float p0 = __builtin_amdgcn_exp2f(sc[0][r] - mi);
            float p1 = __builtin_amdgcn_exp2f(sc[1][r] - mi);
            float p2 = __builtin_amdgcn_exp2f(sc[2][r] - mi);
            float p3 = __builtin_amdgcn_exp2f(sc[3][r] - mi);
            float rs = (p0 + p1) + (p2 + p3);
#pragma unroll
            for (int off = 1; off < 16; off <<= 1)
                rs += __shfl_xor(rs, off, 64);
            l_i[r] += rs;
            st4s(&Ps[w][quad * 4 + r][l16], p0, p1, p2, p3);
        }
        // Ps per-wave private: no barrier (compiler inserts lgkmcnt)

        // PV
        __builtin_amdgcn_s_setprio(1);
#pragma unroll
        for (int kc = 0; kc < 2; ++kc) {
            bf16x8 a = ldfrag(&Ps[w][l16][kc * 32 + quad * 8]);
#pragma unroll
            for (int n = 0; n < 4; ++n) {
                bf16x8 b = ldfrag(&Vt[n * 16 + l16][kc * 32 + quad * 8]);
                acc_o[n] = MFMA(a, b, acc_o[n]);
            }
        }
        __builtin_amdgcn_s_setprio(0);
        __syncthreads();                            // done reading Ks/Vt
        if (kt < SS / 64 - 1) kvstore();
        __syncthreads();                            // new tiles visible
    }

    // epilogue -> ao[B,S,H*64] bf16
    const int b = bh >> 4, h = bh & 15;
#pragma unroll
    for (int r = 0; r < 4; ++r) {
        int srow = qt * 64 + w * 16 + quad * 4 + r;
        float rl = __builtin_amdgcn_rcpf(l_i[r]);
        size_t base = ((size_t)(b * SS + srow)) * (HH * DK) + h * 64;
        st4s(&ao[base + l16], acc_o[0][r] * rl, acc_o[1][r] * rl,
                              acc_o[2][r] * rl, acc_o[3][r] * rl);
    }
}

// ---------------------------------------------------------------------------
// Kernel 3: output projection. BM=BN=128, BK=64, 256 thr (4 waves).
// Wave w owns rows w*32..w*32+31 (2 row-tiles) x all 8 n-tiles -> 32 MFMA
// per k-step per wave. A/B tiles reg-prefetched one k-step ahead (T14).
// ---------------------------------------------------------------------------
__global__ __launch_bounds__(256, 3) void out_proj(
    const u16* __restrict__ ao, const u16* __restrict__ wo_bf,
    float* __restrict__ out)
{
    __shared__ __align__(16) u16 As[128][72];
    __shared__ __align__(16) u16 Bs[128][72];
    const int tid  = threadIdx.x;
    const int w    = tid >> 6;
    const int lane = tid & 63;
    const int quad = lane >> 4;
    const int l16  = lane & 15;
    const int mt = blockIdx.y;
    const int nt = blockIdx.x;

    uint4 areg[4], breg[4];
    auto abload = [&](int kk) {
#pragma unroll
        for (int it = 0; it < 4; ++it) {
            int li = tid + it * 256;
            int r  = li >> 3, c8 = li & 7;
            areg[it] = *(const uint4*)(ao + (size_t)(mt * 128 + r) * DD + kk * 64 + c8 * 8);
            breg[it] = *(const uint4*)(wo_bf + (size_t)(nt * 128 + r) * DD + kk * 64 + c8 * 8);
        }
    };
    auto abstore = [&]() {
#pragma unroll
        for (int it = 0; it < 4; ++it) {
            int li = tid + it * 256;
            int r  = li >> 3, c8 = li & 7;
            *(uint4*)&As[r][c8 * 8] = areg[it];
            *(uint4*)&Bs[r][c8 * 8] = breg[it];
        }
    };

    floatx4 acc[2][8];
#pragma unroll
    for (int rt = 0; rt < 2; ++rt)
#pragma unroll
        for (int n = 0; n < 8; ++n) acc[rt][n] = (floatx4){0.f,0.f,0.f,0.f};

    abload(0); abstore();
    __syncthreads();

    for (int kk = 0; kk < 16; ++kk) {
        if (kk < 15) abload(kk + 1);
#pragma unroll
        for (int kc = 0; kc < 2; ++kc) {
            bf16x8 a0 = ldfrag(&As[w * 32 + l16][kc * 32 + quad * 8]);
            bf16x8 a1 = ldfrag(&As[w * 32 + 16 + l16][kc * 32 + quad * 8]);
#pragma unroll
            for (int n = 0; n < 8; ++n) {
                bf16x8 b = ldfrag(&Bs[n * 16 + l16][kc * 32 + quad * 8]);
                acc[0][n] = MFMA(a0, b, acc[0][n]);
                acc[1][n] = MFMA(a1, b, acc[1][n]);
            }
        }
        __syncthreads();
        if (kk < 15) abstore();
        __syncthreads();
    }

#pragma unroll
    for (int rt = 0; rt < 2; ++rt) {
#pragma unroll
        for (int rr = 0; rr < 4; ++rr) {
            int row = mt * 128 + w * 32 + rt * 16 + quad * 4 + rr;
#pragma unroll
            for (int n = 0; n < 8; ++n)
                out[(size_t)row * DD + nt * 128 + n * 16 + l16] = acc[rt][n][rr];
        }
    }
}

// ---------------------------------------------------------------------------
extern "C" void kernel_launch(void* const* d_in, const int* in_sizes, int n_in,
                              void* d_out, int out_size, void* d_ws, size_t ws_size,
                              hipStream_t stream) {
    const float* x  = (const float*)d_in[0];
    const float* wq = (const float*)d_in[1];
    const float* wk = (const float*)d_in[2];
    const float* wv = (const float*)d_in[3];
    const float* wo = (const float*)d_in[4];
    float* out = (float*)d_out;

    // workspace (bf16): q,k [BHS,64]; vT [B,H,64,S]; ao [B,S,1024];
    // wqkv_bf [192,1024]; wo_bf [1024,1024]   = ~36 MB
    u16* q     = (u16*)d_ws;
    u16* k     = q    + (size_t)BHS * DK;
    u16* vT    = k    + (size_t)BHS * DK;
    u16* ao    = vT   + (size_t)BHS * DK;
    u16* wqkv  = ao   + (size_t)BHS * DK;
    u16* wo_bf = wqkv + (size_t)192 * DD;

    convert_w<<<dim3((WQKV_CHUNKS + WO_CHUNKS) / 256), dim3(256), 0, stream>>>(
        wq, wk, wv, wo, wqkv, wo_bf);
    qkv_proj<<<dim3(BHS / 64), dim3(512), 0, stream>>>(x, wqkv, q, k, vT);
    flash_attn<<<dim3(SS / 64, BB * HH), dim3(256), 0, stream>>>(q, k, vT, ao);
    out_proj<<<dim3(DD / 128, (BB * SS) / 128), dim3(256), 0, stream>>>(ao, wo_bf, out);
}

// Round 3
// 566.611 us; speedup vs baseline: 1.2127x; 1.2127x over previous
//
#include <hip/hip_runtime.h>
#include <math.h>

// Shapes (fixed)
#define BB 2
#define HH 16
#define SS 2048
#define DD 1024
#define DK 64
#define BHS (BB*HH*SS)          // 65536
#define QSCALE 0.04508422f      // log2(e)/sqrt(1024): folded into q so softmax uses exp2

typedef short  bf16x8  __attribute__((ext_vector_type(8)));
typedef float  floatx4 __attribute__((ext_vector_type(4)));
typedef unsigned short u16;

#define MFMA(a,b,c) __builtin_amdgcn_mfma_f32_16x16x32_bf16((a),(b),(c),0,0,0)

// hardware packed conversion: dst.lo = bf16(lo), dst.hi = bf16(hi), RNE
__device__ __forceinline__ unsigned cvt_pk_bf16(float lo, float hi) {
    unsigned r;
    asm("v_cvt_pk_bf16_f32 %0, %1, %2" : "=v"(r) : "v"(lo), "v"(hi));
    return r;
}
__device__ __forceinline__ bf16x8 ldfrag(const u16* p) {
    union { uint4 u; bf16x8 b; } c;
    c.u = *(const uint4*)p;
    return c.b;
}
__device__ __forceinline__ void stbf4(u16* p, float4 t) {  // 4xf32 -> 4xbf16, 8B store
    union { unsigned u[2]; uint2 v; } c;
    c.u[0] = cvt_pk_bf16(t.x, t.y);
    c.u[1] = cvt_pk_bf16(t.z, t.w);
    *(uint2*)p = c.v;
}
// 4 f32 -> bf16 at p[0], p[16], p[32], p[48]  (C-fragment col stride 16)
__device__ __forceinline__ void st4s(u16* p, float a, float b, float c, float d) {
    unsigned x = cvt_pk_bf16(a, b), y = cvt_pk_bf16(c, d);
    p[0]  = (u16)x; p[16] = (u16)(x >> 16);
    p[32] = (u16)y; p[48] = (u16)(y >> 16);
}
// 2 f32 -> bf16 at p[0], p[16]
__device__ __forceinline__ void st2s(u16* p, float a, float b) {
    unsigned x = cvt_pk_bf16(a, b);
    p[0]  = (u16)x; p[16] = (u16)(x >> 16);
}

// ---------------------------------------------------------------------------
// Kernel 0: one-shot weight conversion fp32->bf16 (tiny: ~5 MB read).
// ---------------------------------------------------------------------------
#define WQKV_CHUNKS (192*1024/4)     // 49152 float4 chunks
#define WO_CHUNKS   (1024*1024/4)    // 262144
__global__ __launch_bounds__(256) void convert_w(
    const float* __restrict__ wq, const float* __restrict__ wk,
    const float* __restrict__ wv, const float* __restrict__ wo,
    u16* __restrict__ wqkv, u16* __restrict__ wo_bf)
{
    int i = blockIdx.x * 256 + threadIdx.x;
    if (i < WQKV_CHUNKS) {
        int r = i >> 8;            // row 0..191 (256 float4 per row)
        int c = i & 255;
        const float* src = (r < 64) ? wq : ((r < 128) ? wk : wv);
        float4 t = *(const float4*)(src + (size_t)(r & 63) * DD + c * 4);
        stbf4(wqkv + (size_t)r * DD + c * 4, t);
    } else if (i < WQKV_CHUNKS + WO_CHUNKS) {
        int j = i - WQKV_CHUNKS;
        float4 t = *(const float4*)(wo + (size_t)j * 4);
        stbf4(wo_bf + (size_t)j * 4, t);
    }
}

// ---------------------------------------------------------------------------
// Kernel 1: QKV projection. 512 thr (8 waves), BM=64 rows.
// X is NEVER staged in LDS: each wave loads its MFMA A-fragments directly
// from global (lane quad*16+l16 -> row l16, cols quad*8..+7; 16 rows x 64 B
// full cache lines per instr), 1-step reg prefetch. Only W lives in LDS,
// double-buffered (L2-hot, 24 KB/slice), ONE barrier per k-step.
// Wave (rt = w&3, g = w>>2): rows rt*16.., n-tiles g*6..g*6+5
// (n: 0-3 q, 4-7 k, 8-11 v). No launch_bounds min-waves (avoid spill clamp).
// ---------------------------------------------------------------------------
__global__ __launch_bounds__(512) void qkv_proj(
    const float* __restrict__ x, const u16* __restrict__ wqkv,
    u16* __restrict__ q, u16* __restrict__ k, u16* __restrict__ vT)
{
    __shared__ __align__(16) u16 Ws[2][192][72];   // 55.3 KB double-buffered
    const int tid  = threadIdx.x;
    const int w    = tid >> 6;
    const int lane = tid & 63;
    const int quad = lane >> 4;
    const int l16  = lane & 15;
    const int rt   = w & 3;
    const int g    = w >> 2;
    const int rowbase = blockIdx.x * 64;
    const float* xr = x + (size_t)(rowbase + rt * 16 + l16) * DD + quad * 8;

    uint4 wreg[3];
    auto wload = [&](int kk) {
#pragma unroll
        for (int it = 0; it < 3; ++it) {
            int li = tid + it * 512;
            int r  = li >> 3, c8 = li & 7;
            wreg[it] = *(const uint4*)(wqkv + (size_t)r * DD + kk * 64 + c8 * 8);
        }
    };
    auto wstore = [&](int p) {
#pragma unroll
        for (int it = 0; it < 3; ++it) {
            int li = tid + it * 512;
            int r  = li >> 3, c8 = li & 7;
            *(uint4*)&Ws[p][r][c8 * 8] = wreg[it];
        }
    };

    float4 xc[4], xn[4];
    auto xload = [&](int kk, float4* d) {
        const float* p = xr + kk * 64;
        d[0] = *(const float4*)(p);
        d[1] = *(const float4*)(p + 4);
        d[2] = *(const float4*)(p + 32);
        d[3] = *(const float4*)(p + 36);
    };

    floatx4 acc[6];
#pragma unroll
    for (int j = 0; j < 6; ++j) acc[j] = (floatx4){0.f,0.f,0.f,0.f};

    wload(0); wstore(0);
    xload(0, xc);
    __syncthreads();

    for (int kk = 0; kk < 16; ++kk) {
        int p = kk & 1;
        if (kk < 15) { wload(kk + 1); xload(kk + 1, xn); }
        // build A fragments from xc (f32 -> bf16, RNE)
        union { unsigned u[4]; bf16x8 v; } A0, A1;
        A0.u[0] = cvt_pk_bf16(xc[0].x, xc[0].y);
        A0.u[1] = cvt_pk_bf16(xc[0].z, xc[0].w);
        A0.u[2] = cvt_pk_bf16(xc[1].x, xc[1].y);
        A0.u[3] = cvt_pk_bf16(xc[1].z, xc[1].w);
        A1.u[0] = cvt_pk_bf16(xc[2].x, xc[2].y);
        A1.u[1] = cvt_pk_bf16(xc[2].z, xc[2].w);
        A1.u[2] = cvt_pk_bf16(xc[3].x, xc[3].y);
        A1.u[3] = cvt_pk_bf16(xc[3].z, xc[3].w);
#pragma unroll
        for (int j = 0; j < 6; ++j) {
            int n = g * 6 + j;
            bf16x8 b0 = ldfrag(&Ws[p][n * 16 + l16][quad * 8]);
            bf16x8 b1 = ldfrag(&Ws[p][n * 16 + l16][32 + quad * 8]);
            acc[j] = MFMA(A0.v, b0, acc[j]);
            acc[j] = MFMA(A1.v, b1, acc[j]);
        }
        if (kk < 15) {
            wstore(p ^ 1);
#pragma unroll
            for (int i2 = 0; i2 < 4; ++i2) xc[i2] = xn[i2];
            __syncthreads();        // Ws[p^1] visible for step kk+1
        }
    }

    // epilogue: global row = rowbase + rt*16 + quad*4 + rr; col = n*16 + l16
    // Vbuf overlays Ws[0] (step 15 reads Ws[1] only - no race)
    u16 (*Vbuf)[72] = (u16 (*)[72])&Ws[0][0][0];
#pragma unroll
    for (int rr = 0; rr < 4; ++rr) {
        int rloc = rt * 16 + quad * 4 + rr;
        size_t m = (size_t)(rowbase + rloc);
        if (g == 0) {
            st4s(&q[m * DK + l16], acc[0][rr] * QSCALE, acc[1][rr] * QSCALE,
                                   acc[2][rr] * QSCALE, acc[3][rr] * QSCALE);
            st2s(&k[m * DK + l16], acc[4][rr], acc[5][rr]);          // k cols 0..31
        } else {
            st2s(&k[m * DK + 32 + l16], acc[0][rr], acc[1][rr]);     // k cols 32..63
            st4s(&Vbuf[rloc][l16], acc[2][rr], acc[3][rr],           // v -> Vbuf
                                   acc[4][rr], acc[5][rr]);
        }
    }
    __syncthreads();
    {   // vT[(bh*64+dk)*2048 + s] transpose write, 16 B per thread
        const int dk = tid >> 3;
        const int sc = (tid & 7) * 8;
        const int bh = rowbase >> 11;
        const int s0 = rowbase & 2047;
        union { u16 s[8]; uint4 u; } t;
#pragma unroll
        for (int u = 0; u < 8; ++u) t.s[u] = Vbuf[sc + u][dk];
        *(uint4*)(vT + ((size_t)(bh * DK + dk)) * SS + s0 + sc) = t.u;
    }
}

// ---------------------------------------------------------------------------
// Kernel 2: flash attention, bf16 MFMA, online softmax in log2 domain.
// (reverted to the 574 us-benched version: no reg prefetch, no occupancy clamp)
// ---------------------------------------------------------------------------
__global__ __launch_bounds__(256) void flash_attn(
    const u16* __restrict__ q, const u16* __restrict__ k,
    const u16* __restrict__ vT, u16* __restrict__ ao)
{
    __shared__ __align__(16) u16 Qs[64][72];
    __shared__ __align__(16) u16 Ks[64][72];
    __shared__ __align__(16) u16 Vt[64][72];       // Vt[dk][t]
    __shared__ __align__(16) u16 Ps[4][16][72];    // per-wave P tile
    const int tid  = threadIdx.x;
    const int w    = tid >> 6;
    const int lane = tid & 63;
    const int quad = lane >> 4;
    const int l16  = lane & 15;
    const int qt   = blockIdx.x;
    const int bh   = blockIdx.y;
    const size_t kbase = (size_t)bh * SS * DK;     // q,k layout [bh*S + t][64]
    const size_t vbase = (size_t)bh * DK * SS;     // vT layout [bh*64 + dk][S]

    // load Q tile once (512 uint4 chunks, 2/thread)
#pragma unroll
    for (int it = 0; it < 2; ++it) {
        int li = tid + it * 256;
        int r  = li >> 3, c8 = li & 7;
        *(uint4*)&Qs[r][c8 * 8] =
            *(const uint4*)(q + kbase + (size_t)(qt * 64 + r) * DK + c8 * 8);
    }

    float m_i[4], l_i[4];
    floatx4 acc_o[4];
#pragma unroll
    for (int r = 0; r < 4; ++r) { m_i[r] = -INFINITY; l_i[r] = 0.f; }
#pragma unroll
    for (int n = 0; n < 4; ++n) acc_o[n] = (floatx4){0.f,0.f,0.f,0.f};
    __syncthreads();

    for (int kt = 0; kt < SS / 64; ++kt) {
        // stage K tile [64 t][64 dk] and Vt tile [64 dk][64 t]
#pragma unroll
        for (int it = 0; it < 2; ++it) {
            int li = tid + it * 256;
            int r  = li >> 3, c8 = li & 7;
            *(uint4*)&Ks[r][c8 * 8] =
                *(const uint4*)(k + kbase + (size_t)(kt * 64 + r) * DK + c8 * 8);
            *(uint4*)&Vt[r][c8 * 8] =
                *(const uint4*)(vT + vbase + (size_t)r * SS + kt * 64 + c8 * 8);
        }
        __syncthreads();

        // scores (log2 units)
        floatx4 sc[4];
        __builtin_amdgcn_s_setprio(1);
        {
            bf16x8 a0 = ldfrag(&Qs[w * 16 + l16][quad * 8]);
            bf16x8 a1 = ldfrag(&Qs[w * 16 + l16][32 + quad * 8]);
#pragma unroll
            for (int n = 0; n < 4; ++n) {
                sc[n] = (floatx4){0.f,0.f,0.f,0.f};
                bf16x8 b0 = ldfrag(&Ks[n * 16 + l16][quad * 8]);
                bf16x8 b1 = ldfrag(&Ks[n * 16 + l16][32 + quad * 8]);
                sc[n] = MFMA(a0, b0, sc[n]);
                sc[n] = MFMA(a1, b1, sc[n]);
            }
        }
        __builtin_amdgcn_s_setprio(0);

        // row maxima (row = quad*4+r), 16-lane butterfly
        float rmx[4];
#pragma unroll
        for (int r = 0; r < 4; ++r) {
            float rm = fmaxf(fmaxf(sc[0][r], sc[1][r]), fmaxf(sc[2][r], sc[3][r]));
#pragma unroll
            for (int off = 1; off < 16; off <<= 1)
                rm = fmaxf(rm, __shfl_xor(rm, off, 64));
            rmx[r] = rm;
        }
        // defer-max (THR=8 in log2 units)
        int ok = (rmx[0] <= m_i[0] + 8.f) & (rmx[1] <= m_i[1] + 8.f) &
                 (rmx[2] <= m_i[2] + 8.f) & (rmx[3] <= m_i[3] + 8.f);
        if (!__all(ok)) {
#pragma unroll
            for (int r = 0; r < 4; ++r) {
                float mnew  = fmaxf(m_i[r], rmx[r]);
                float alpha = __builtin_amdgcn_exp2f(m_i[r] - mnew);
#pragma unroll
                for (int n = 0; n < 4; ++n) acc_o[n][r] *= alpha;
                l_i[r] *= alpha;
                m_i[r]  = mnew;
            }
        }
        // P = exp2(S - m), row sums, P -> LDS
#pragma unroll
        for (int r = 0; r < 4; ++r) {
            float mi = m_i[r];
            float p0 = __builtin_amdgcn_exp2f(sc[0][r] - mi);
            float p1 = __builtin_amdgcn_exp2f(sc[1][r] - mi);
            float p2 = __builtin_amdgcn_exp2f(sc[2][r] - mi);
            float p3 = __builtin_amdgcn_exp2f(sc[3][r] - mi);
            float rs = (p0 + p1) + (p2 + p3);
#pragma unroll
            for (int off = 1; off < 16; off <<= 1)
                rs += __shfl_xor(rs, off, 64);
            l_i[r] += rs;
            st4s(&Ps[w][quad * 4 + r][l16], p0, p1, p2, p3);
        }
        // Ps per-wave private: no barrier (compiler inserts lgkmcnt)

        // PV
        __builtin_amdgcn_s_setprio(1);
#pragma unroll
        for (int kc = 0; kc < 2; ++kc) {
            bf16x8 a = ldfrag(&Ps[w][l16][kc * 32 + quad * 8]);
#pragma unroll
            for (int n = 0; n < 4; ++n) {
                bf16x8 b = ldfrag(&Vt[n * 16 + l16][kc * 32 + quad * 8]);
                acc_o[n] = MFMA(a, b, acc_o[n]);
            }
        }
        __builtin_amdgcn_s_setprio(0);
        __syncthreads();                            // done reading Ks/Vt
    }

    // epilogue -> ao[B,S,H*64] bf16
    const int b = bh >> 4, h = bh & 15;
#pragma unroll
    for (int r = 0; r < 4; ++r) {
        int srow = qt * 64 + w * 16 + quad * 4 + r;
        float rl = __builtin_amdgcn_rcpf(l_i[r]);
        size_t base = ((size_t)(b * SS + srow)) * (HH * DK) + h * 64;
        st4s(&ao[base + l16], acc_o[0][r] * rl, acc_o[1][r] * rl,
                              acc_o[2][r] * rl, acc_o[3][r] * rl);
    }
}

// ---------------------------------------------------------------------------
// Kernel 3: output projection, bf16 MFMA. out[4096,1024] = ao @ wo^T (fp32).
// (reverted to the 574 us-benched version)
// ---------------------------------------------------------------------------
__global__ __launch_bounds__(256) void out_proj(
    const u16* __restrict__ ao, const u16* __restrict__ wo_bf,
    float* __restrict__ out)
{
    __shared__ __align__(16) u16 As[64][72];
    __shared__ __align__(16) u16 Bs[64][72];
    const int tid  = threadIdx.x;
    const int w    = tid >> 6;
    const int lane = tid & 63;
    const int quad = lane >> 4;
    const int l16  = lane & 15;
    const int mt = blockIdx.y;
    const int nt = blockIdx.x;

    floatx4 acc[4];
#pragma unroll
    for (int n = 0; n < 4; ++n) acc[n] = (floatx4){0.f,0.f,0.f,0.f};

    for (int k0 = 0; k0 < DD; k0 += 64) {
#pragma unroll
        for (int it = 0; it < 2; ++it) {
            int li = tid + it * 256;
            int r  = li >> 3, c8 = li & 7;
            *(uint4*)&As[r][c8 * 8] =
                *(const uint4*)(ao + (size_t)(mt * 64 + r) * DD + k0 + c8 * 8);
            *(uint4*)&Bs[r][c8 * 8] =
                *(const uint4*)(wo_bf + (size_t)(nt * 64 + r) * DD + k0 + c8 * 8);
        }
        __syncthreads();

        bf16x8 a0 = ldfrag(&As[w * 16 + l16][quad * 8]);
        bf16x8 a1 = ldfrag(&As[w * 16 + l16][32 + quad * 8]);
#pragma unroll
        for (int n = 0; n < 4; ++n) {
            bf16x8 b0 = ldfrag(&Bs[n * 16 + l16][quad * 8]);
            bf16x8 b1 = ldfrag(&Bs[n * 16 + l16][32 + quad * 8]);
            acc[n] = MFMA(a0, b0, acc[n]);
            acc[n] = MFMA(a1, b1, acc[n]);
        }
        __syncthreads();
    }

#pragma unroll
    for (int r = 0; r < 4; ++r) {
        int row = mt * 64 + w * 16 + quad * 4 + r;
#pragma unroll
        for (int n = 0; n < 4; ++n)
            out[(size_t)row * DD + nt * 64 + n * 16 + l16] = acc[n][r];
    }
}

// ---------------------------------------------------------------------------
extern "C" void kernel_launch(void* const* d_in, const int* in_sizes, int n_in,
                              void* d_out, int out_size, void* d_ws, size_t ws_size,
                              hipStream_t stream) {
    const float* x  = (const float*)d_in[0];
    const float* wq = (const float*)d_in[1];
    const float* wk = (const float*)d_in[2];
    const float* wv = (const float*)d_in[3];
    const float* wo = (const float*)d_in[4];
    float* out = (float*)d_out;

    // workspace (bf16): q,k [BHS,64]; vT [B,H,64,S]; ao [B,S,1024];
    // wqkv_bf [192,1024]; wo_bf [1024,1024]   = ~36 MB
    u16* q     = (u16*)d_ws;
    u16* k     = q    + (size_t)BHS * DK;
    u16* vT    = k    + (size_t)BHS * DK;
    u16* ao    = vT   + (size_t)BHS * DK;
    u16* wqkv  = ao   + (size_t)BHS * DK;
    u16* wo_bf = wqkv + (size_t)192 * DD;

    convert_w<<<dim3((WQKV_CHUNKS + WO_CHUNKS) / 256), dim3(256), 0, stream>>>(
        wq, wk, wv, wo, wqkv, wo_bf);
    qkv_proj<<<dim3(BHS / 64), dim3(512), 0, stream>>>(x, wqkv, q, k, vT);
    flash_attn<<<dim3(SS / 64, BB * HH), dim3(256), 0, stream>>>(q, k, vT, ao);
    out_proj<<<dim3(DD / 64, (BB * SS) / 64), dim3(256), 0, stream>>>(ao, wo_bf, out);
}